// Round 5
// baseline (627.911 us; speedup 1.0000x reference)
//
#include <hip/hip_runtime.h>
#include <cstdint>
#include <cstddef>

#define Nn   50000
#define Ee   800000
#define ETOT 850000   // edges + self loops
#define HID  128
#define Gg   16
#define RSZ  6250     // Nn/8 : dst-range size per XCD team
#define DMAX 64       // padded adjacency slots per node (max degree ~45 for this graph)
#define NEG_SLOPE 0.2f
#define EPS_GN 1e-5f

typedef __attribute__((ext_vector_type(8))) short short8;
typedef __attribute__((ext_vector_type(4))) float f32x4;

static __device__ __forceinline__ float lrelu(float v) { return v > 0.f ? v : NEG_SLOPE * v; }

// round-to-nearest-even fp32 -> bf16 (low 16 bits of uint)
static __device__ __forceinline__ unsigned int f2bf(float x) {
    unsigned int u = __float_as_uint(x);
    return (u + 0x7fffu + ((u >> 16) & 1u)) >> 16;
}
static __device__ __forceinline__ float bf_lo(unsigned int u) { return __uint_as_float(u << 16); }
static __device__ __forceinline__ float bf_hi(unsigned int u) { return __uint_as_float(u & 0xffff0000u); }

// ---------------------------------------------------------------------------
// Weight prep: bf16 transpose of in_W [64][128]->Wt0[128][64] and
// Wg[4][128][128]->Wtl[4][128][128] ([n][k] layout)
// ---------------------------------------------------------------------------
__global__ void prep_w(const float* __restrict__ in_W, const float* __restrict__ Wg,
                       short* __restrict__ Wt0, short* __restrict__ Wtl) {
    int i = blockIdx.x * 256 + threadIdx.x;
    if (i < 8192) {                       // in-proj: n = i>>6, k = i&63
        int n = i >> 6, k = i & 63;
        Wt0[i] = (short)f2bf(in_W[k * 128 + n]);
    } else if (i < 73728) {
        int j = i - 8192;                 // j = l*16384 + n*128 + k
        int l = j >> 14;
        int rkn = j & 16383;
        int n = rkn >> 7, k = rkn & 127;
        Wtl[j] = (short)f2bf(Wg[l * 16384 + k * 128 + n]);
    }
}

// ---------------------------------------------------------------------------
// Padded adjacency build, single pass, XCD-partitioned (block b&7 = dst range,
// so cnt/colPad cache lines have a single-XCD writer).
// R0: 8192 blocks (team traffic is grid-invariant), int4 scan, self-loops as a
// separate team-local loop. Verified: dropped out of top-5.
// ---------------------------------------------------------------------------
__global__ __launch_bounds__(256) void scatter_pad(const int* __restrict__ esrc,
                                                   const int* __restrict__ edst,
                                                   int* __restrict__ cnt,
                                                   int* __restrict__ colPad) {
    int r  = blockIdx.x & 7;
    int cb = blockIdx.x >> 3;
    int nb = gridDim.x >> 3;
    int lo = r * RSZ, hi = lo + RSZ;
    int stride = nb * 256 * 4;
    for (int i = (cb * 256 + threadIdx.x) * 4; i < Ee; i += stride) {
        int4 d4 = *(const int4*)(edst + i);
        bool m0 = (d4.x >= lo) & (d4.x < hi);
        bool m1 = (d4.y >= lo) & (d4.y < hi);
        bool m2 = (d4.z >= lo) & (d4.z < hi);
        bool m3 = (d4.w >= lo) & (d4.w < hi);
        if (m0 | m1 | m2 | m3) {
            int4 s4 = *(const int4*)(esrc + i);
            if (m0) { int pos = atomicAdd(&cnt[d4.x], 1); if (pos < DMAX) colPad[d4.x * DMAX + pos] = s4.x; }
            if (m1) { int pos = atomicAdd(&cnt[d4.y], 1); if (pos < DMAX) colPad[d4.y * DMAX + pos] = s4.y; }
            if (m2) { int pos = atomicAdd(&cnt[d4.z], 1); if (pos < DMAX) colPad[d4.z * DMAX + pos] = s4.z; }
            if (m3) { int pos = atomicAdd(&cnt[d4.w], 1); if (pos < DMAX) colPad[d4.w * DMAX + pos] = s4.w; }
        }
    }
    // self-loops: each team owns its dst range; dst == src == n, no edge loads
    for (int n = lo + cb * 256 + threadIdx.x; n < hi; n += nb * 256) {
        int pos = atomicAdd(&cnt[n], 1);
        if (pos < DMAX) colPad[n * DMAX + pos] = n;
    }
}

// ---------------------------------------------------------------------------
// MFMA bf16 GEMM: C[M,128] = affine?(A)[M,K] @ W[K,128] (+bias), bf16x2 out.
// Block 128x128, 4 waves (2x2 of 64x64), 16x16x32 bf16 MFMA.
// ABF16: A is packed bf16x2 [M, K/2 uints]; else fp32 [M,K].
// SCORES: fused es/ed (attention logits) computed during the repack read-out.
// ---------------------------------------------------------------------------
template <int K, bool ABF16, bool AFFINE, bool BIAS, bool SCORES>
__global__ __launch_bounds__(256) void gemm_mfma(const float* __restrict__ Agf,
                                                 const unsigned int* __restrict__ Agb,
                                                 const int* __restrict__ batch,
                                                 const float* __restrict__ Ab,
                                                 const float* __restrict__ Bb,
                                                 const short* __restrict__ Wt,
                                                 const float* __restrict__ bias,
                                                 const float* __restrict__ asrc,
                                                 const float* __restrict__ adst,
                                                 float* __restrict__ es,
                                                 float* __restrict__ ed,
                                                 unsigned int* __restrict__ Cb,
                                                 int M) {
    constexpr int KP = K + 8;                    // padded shorts per A row
    constexpr int ABYTES = 128 * KP * 2;
    constexpr int CBYTES = 64 * 130 * 4;
    constexpr int SBYTES = ABYTES > CBYTES ? ABYTES : CBYTES;
    __shared__ __align__(16) char smem[SBYTES];
    short* As = (short*)smem;
    float* Cs = (float*)smem;   // overlays As (used only after all MFMA reads)

    int t    = threadIdx.x;
    int lane = t & 63;
    int w    = t >> 6;
    int wm   = (w & 1) * 64;
    int wn   = (w >> 1) * 64;
    int row0 = blockIdx.x * 128;

    // ---- stage A -> bf16 LDS ----
    if (!ABF16) {
        constexpr int F4R = K / 4;               // float4 per row
        constexpr int ITERS = 128 * F4R / 256;
#pragma unroll
        for (int i = 0; i < ITERS; i++) {
            int f4 = t + 256 * i;
            int r  = f4 / F4R;
            int c4 = f4 % F4R;
            float4 v = make_float4(0.f, 0.f, 0.f, 0.f);
            int gr = row0 + r;
            if (gr < M) v = *(const float4*)(Agf + (size_t)gr * K + c4 * 4);
            uint2 pk;
            pk.x = f2bf(v.x) | (f2bf(v.y) << 16);
            pk.y = f2bf(v.z) | (f2bf(v.w) << 16);
            *(uint2*)(As + r * KP + c4 * 4) = pk;
        }
    } else {
        constexpr int U2R = K / 4;               // uint2 per row
        constexpr int ITERS = 128 * U2R / 256;
#pragma unroll
        for (int i = 0; i < ITERS; i++) {
            int u2 = t + 256 * i;
            int r  = u2 / U2R;
            int c2 = u2 % U2R;                   // uint2 index: channels c2*4..+3
            uint2 v = make_uint2(0u, 0u);
            int gr = row0 + r;
            if (gr < M) {
                v = *(const uint2*)(Agb + (size_t)gr * (K / 2) + c2 * 2);
                if (AFFINE) {
                    int g = batch[gr];
                    float4 Av = *(const float4*)(Ab + g * 128 + c2 * 4);
                    float4 Bv = *(const float4*)(Bb + g * 128 + c2 * 4);
                    float x0 = bf_lo(v.x) * Av.x + Bv.x;
                    float x1 = bf_hi(v.x) * Av.y + Bv.y;
                    float x2 = bf_lo(v.y) * Av.z + Bv.z;
                    float x3 = bf_hi(v.y) * Av.w + Bv.w;
                    v.x = f2bf(x0) | (f2bf(x1) << 16);
                    v.y = f2bf(x2) | (f2bf(x3) << 16);
                }
            }
            *(uint2*)(As + r * KP + c2 * 4) = v;
        }
    }
    __syncthreads();

    // ---- MFMA main loop ----
    f32x4 acc[4][4] = {};
    int am = wm + (lane & 15);
    int aq = (lane >> 4) * 8;
    const short* wb = Wt + (size_t)(wn + (lane & 15)) * K + aq;
#pragma unroll
    for (int kk = 0; kk < K / 32; kk++) {
        short8 a[4], b[4];
#pragma unroll
        for (int nt = 0; nt < 4; nt++)
            b[nt] = *(const short8*)(wb + nt * 16 * K + kk * 32);
#pragma unroll
        for (int mt = 0; mt < 4; mt++)
            a[mt] = *(const short8*)(As + (am + mt * 16) * KP + kk * 32 + aq);
#pragma unroll
        for (int mt = 0; mt < 4; mt++)
#pragma unroll
            for (int nt = 0; nt < 4; nt++)
                acc[mt][nt] = __builtin_amdgcn_mfma_f32_16x16x32_bf16(
                    a[mt], b[nt], acc[mt][nt], 0, 0, 0);
    }

    // ---- epilogue: LDS repack -> packed bf16x2 (+bias, + fused scores) ----
    // C/D layout: col = lane&15 (within 16-tile), row = (lane>>4)*4 + reg
    float bv[4] = {0.f, 0.f, 0.f, 0.f};
    if (BIAS) {
#pragma unroll
        for (int nt = 0; nt < 4; nt++) bv[nt] = bias[wn + nt * 16 + (lane & 15)];
    }
    float avv[8], dvv[8];
    if (SCORES) {
        int q = t & 15;
#pragma unroll
        for (int k = 0; k < 8; k++) {
            avv[k] = asrc[q * 8 + k];
            dvv[k] = adst[q * 8 + k];
        }
    }
#pragma unroll
    for (int half = 0; half < 2; half++) {
        __syncthreads();   // As reads done / previous pack done
        if ((w & 1) == half) {
#pragma unroll
            for (int mt = 0; mt < 4; mt++)
#pragma unroll
                for (int reg = 0; reg < 4; reg++) {
                    int lr = mt * 16 + (lane >> 4) * 4 + reg;   // 0..63
#pragma unroll
                    for (int nt = 0; nt < 4; nt++)
                        Cs[lr * 130 + wn + nt * 16 + (lane & 15)] =
                            acc[mt][nt][reg] + bv[nt];
                }
        }
        __syncthreads();
#pragma unroll
        for (int i = 0; i < 4; i++) {
            int u4 = t + 256 * i;       // 0..1023
            int r  = u4 >> 4;           // 0..63
            int cu = (u4 & 15) * 4;     // uint col
            int grow = row0 + half * 64 + r;
            if (grow < M) {
                const float* cp = Cs + r * 130 + cu * 2;
                float2 p0 = *(const float2*)(cp + 0);
                float2 p1 = *(const float2*)(cp + 2);
                float2 p2 = *(const float2*)(cp + 4);
                float2 p3 = *(const float2*)(cp + 6);
                uint4 o;
                o.x = f2bf(p0.x) | (f2bf(p0.y) << 16);
                o.y = f2bf(p1.x) | (f2bf(p1.y) << 16);
                o.z = f2bf(p2.x) | (f2bf(p2.y) << 16);
                o.w = f2bf(p3.x) | (f2bf(p3.y) << 16);
                *(uint4*)(Cb + (size_t)grow * 64 + cu) = o;
                if (SCORES) {
                    float s1 = p0.x * avv[0] + p0.y * avv[1] + p1.x * avv[2] +
                               p1.y * avv[3] + p2.x * avv[4] + p2.y * avv[5] +
                               p3.x * avv[6] + p3.y * avv[7];
                    float s2 = p0.x * dvv[0] + p0.y * dvv[1] + p1.x * dvv[2] +
                               p1.y * dvv[3] + p2.x * dvv[4] + p2.y * dvv[5] +
                               p3.x * dvv[6] + p3.y * dvv[7];
                    s1 += __shfl_xor(s1, 1);
                    s2 += __shfl_xor(s2, 1);
                    if ((t & 1) == 0) {
                        int hh = (t & 15) >> 1;
                        es[(size_t)grow * 8 + hh] = s1;
                        ed[(size_t)grow * 8 + hh] = s2;
                    }
                }
            }
        }
    }
}

// ---------------------------------------------------------------------------
// GAT aggregation. One wave per destination node, persistent grid-stride.
// R3 rework (re-run in R4: prior bench was an infra failure, kernel unmeasured).
// R2 post-mortem: compiler re-fused weight+accumulate phases (VGPR stayed 28
// -> sg/wg never lived) because accumulate used un-normalized weights. Fix:
// normalize wg by the softmax denominator BEFORE accumulate -- inv depends on
// ALL wg via the wave reduction, so the compiler CANNOT sink weight-phase
// gathers into the accumulate loop. Result: 8 cb loads + 8 es gathers issue
// as a batch, then ~16 independent hp gathers (shfl-addressed) -> deep MLP in
// both phases. Persistent 2048-block grid removes block churn.
// Lane roles: weight (slot=lane>>3, head=lane&7); accumulate (q=lane>>4,
// s=lane&15 holds channels 8s..8s+7, uint4 gather); head hd = s>>1.
// Check in counters: VGPR should now be ~48-64 (28 = compiler defeated us).
// ---------------------------------------------------------------------------
template <bool AFF>
__global__ __launch_bounds__(256) void gat_attn(const unsigned int* __restrict__ hp,
                                                const unsigned int* hinb,
                                                const int* __restrict__ batch,
                                                const float* __restrict__ Ab,
                                                const float* __restrict__ Bb,
                                                const float* __restrict__ es,
                                                const float* __restrict__ ed,
                                                const int* __restrict__ cnt,
                                                const int* __restrict__ colPad,
                                                const float* __restrict__ gbias,
                                                unsigned int* outb) {
    int w    = threadIdx.x >> 6;
    int lane = threadIdx.x & 63;

    int slot = lane >> 3;   // edge slot (weight phase)
    int ah   = lane & 7;    // head (weight phase)
    int q    = lane >> 4;   // edge parity mod 4 (accumulate phase)
    int s    = lane & 15;   // channel group: channels 8s .. 8s+7 (uint4 index s)
    int hd   = s >> 1;      // head of this lane's channels

    const uint4* hp4 = (const uint4*)hp + s;    // + sj*16 per row

    for (int n = blockIdx.x * 4 + w; n < Nn; n += gridDim.x * 4) {
        int deg = cnt[n];
        deg = deg < DMAX ? deg : DMAX;
        const int* cb = colPad + n * DMAX;
        float edh = ed[(size_t)n * 8 + ah];

        // ---- weight phase: all groups up-front (deg <= 64 = 8 groups) ----
        int   sg[8];
        float wg[8];
        int ngrp = (deg + 7) >> 3;   // 1..8, wave-uniform
#pragma unroll 8
        for (int g = 0; g < 8; g++) {
            sg[g] = 0;
            wg[g] = 0.f;
            if (g < ngrp) {
                int e  = g * 8 + slot;
                int ec = (e < deg) ? e : (deg - 1);   // row non-empty (self-loop)
                int sl = cb[ec];
                sg[g] = sl;
                wg[g] = (e < deg) ? __expf(lrelu(es[(size_t)sl * 8 + ah] + edh)) : 0.f;
            }
        }

        // softmax denominator over the 8 slots sharing head `ah`
        float dacc = 0.f;
#pragma unroll 8
        for (int g = 0; g < 8; g++) dacc += wg[g];
        dacc += __shfl_xor(dacc, 8);
        dacc += __shfl_xor(dacc, 16);
        dacc += __shfl_xor(dacc, 32);
        float inv = 1.0f / (dacc + 1e-16f);
        // normalize BEFORE accumulate: data dependency pins the phase split
#pragma unroll 8
        for (int g = 0; g < 8; g++) wg[g] *= inv;

        // ---- accumulate phase: 4 edges in flight per step, all independent ----
        float a0 = 0.f, a1 = 0.f, a2 = 0.f, a3 = 0.f;
        float a4 = 0.f, a5 = 0.f, a6 = 0.f, a7 = 0.f;
#pragma unroll 8
        for (int g = 0; g < 8; g++) {
#pragma unroll 2
            for (int jj = 0; jj < 2; jj++) {
                if (g * 8 + jj * 4 < deg) {           // wave-uniform
                    int e = jj * 4 + q;               // weights beyond deg are 0
                    int   sj = __shfl(sg[g], e * 8);
                    float wj = __shfl(wg[g], e * 8 + hd);
                    uint4 hv = hp4[(size_t)sj * 16];
                    a0 += wj * bf_lo(hv.x);
                    a1 += wj * bf_hi(hv.x);
                    a2 += wj * bf_lo(hv.y);
                    a3 += wj * bf_hi(hv.y);
                    a4 += wj * bf_lo(hv.z);
                    a5 += wj * bf_hi(hv.z);
                    a6 += wj * bf_lo(hv.w);
                    a7 += wj * bf_hi(hv.w);
                }
            }
        }

        // combine the four quarters (each saw edges of one parity mod 4)
        a0 += __shfl_xor(a0, 16); a0 += __shfl_xor(a0, 32);
        a1 += __shfl_xor(a1, 16); a1 += __shfl_xor(a1, 32);
        a2 += __shfl_xor(a2, 16); a2 += __shfl_xor(a2, 32);
        a3 += __shfl_xor(a3, 16); a3 += __shfl_xor(a3, 32);
        a4 += __shfl_xor(a4, 16); a4 += __shfl_xor(a4, 32);
        a5 += __shfl_xor(a5, 16); a5 += __shfl_xor(a5, 32);
        a6 += __shfl_xor(a6, 16); a6 += __shfl_xor(a6, 32);
        a7 += __shfl_xor(a7, 16); a7 += __shfl_xor(a7, 32);

        if (q == 0) {
            size_t uo = (size_t)n * 64 + s * 4;
            uint4 xv = *(const uint4*)(hinb + uo);
            float r0 = bf_lo(xv.x), r1 = bf_hi(xv.x), r2 = bf_lo(xv.y), r3 = bf_hi(xv.y);
            float r4 = bf_lo(xv.z), r5 = bf_hi(xv.z), r6 = bf_lo(xv.w), r7 = bf_hi(xv.w);
            float4 bv0 = *(const float4*)(gbias + s * 8);
            float4 bv1 = *(const float4*)(gbias + s * 8 + 4);
            if (AFF) {
                int g = batch[n];
                float4 Av0 = *(const float4*)(Ab + g * 128 + s * 8);
                float4 Bv0 = *(const float4*)(Bb + g * 128 + s * 8);
                float4 Av1 = *(const float4*)(Ab + g * 128 + s * 8 + 4);
                float4 Bv1 = *(const float4*)(Bb + g * 128 + s * 8 + 4);
                r0 = r0 * Av0.x + Bv0.x;
                r1 = r1 * Av0.y + Bv0.y;
                r2 = r2 * Av0.z + Bv0.z;
                r3 = r3 * Av0.w + Bv0.w;
                r4 = r4 * Av1.x + Bv1.x;
                r5 = r5 * Av1.y + Bv1.y;
                r6 = r6 * Av1.z + Bv1.z;
                r7 = r7 * Av1.w + Bv1.w;
            }
            float o0 = a0 + bv0.x + r0;
            float o1 = a1 + bv0.y + r1;
            float o2 = a2 + bv0.z + r2;
            float o3 = a3 + bv0.w + r3;
            float o4 = a4 + bv1.x + r4;
            float o5 = a5 + bv1.y + r5;
            float o6 = a6 + bv1.z + r6;
            float o7 = a7 + bv1.w + r7;
            uint4 o;
            o.x = f2bf(o0) | (f2bf(o1) << 16);
            o.y = f2bf(o2) | (f2bf(o3) << 16);
            o.z = f2bf(o4) | (f2bf(o5) << 16);
            o.w = f2bf(o6) | (f2bf(o7) << 16);
            *(uint4*)(outb + uo) = o;
        }
    }
}

// ---------------------------------------------------------------------------
// GraphNorm stats (bf16 input): per (g,c) sum/sumsq; batch sorted -> run flush.
// ---------------------------------------------------------------------------
#define SCHUNK 32
__global__ __launch_bounds__(128) void gn_stats(const unsigned int* __restrict__ xb,
                                                const int* __restrict__ batch,
                                                float* __restrict__ sumx,
                                                float* __restrict__ sumxx,
                                                float* __restrict__ cnt) {
    int c  = threadIdx.x;
    int cu = c >> 1;
    int hi = c & 1;
    int n0 = blockIdx.x * SCHUNK;
    int n1 = n0 + SCHUNK;
    if (n1 > Nn) n1 = Nn;
    if (n0 >= Nn) return;
    int curG = batch[n0];
    float sx = 0.f, sxx = 0.f;
    int run = 0;
    for (int n = n0; n < n1; n++) {
        int g = batch[n];
        if (g != curG) {
            atomicAdd(&sumx[curG * 128 + c], sx);
            atomicAdd(&sumxx[curG * 128 + c], sxx);
            if (c == 0) atomicAdd(&cnt[curG], (float)run);
            sx = 0.f; sxx = 0.f; run = 0; curG = g;
        }
        unsigned int u = xb[(size_t)n * 64 + cu];
        float v = hi ? bf_hi(u) : bf_lo(u);
        sx += v; sxx += v * v; run++;
    }
    atomicAdd(&sumx[curG * 128 + c], sx);
    atomicAdd(&sumxx[curG * 128 + c], sxx);
    if (c == 0) atomicAdd(&cnt[curG], (float)run);
}

// computes Ab/Bb then zeroes sumx/sumxx/cnt for the next layer's gn_stats
__global__ void gn_final(float* __restrict__ sumx, float* __restrict__ sumxx,
                         float* __restrict__ cnt, const float* __restrict__ w,
                         const float* __restrict__ b, const float* __restrict__ s,
                         float* __restrict__ Ab, float* __restrict__ Bb) {
    int i = blockIdx.x * blockDim.x + threadIdx.x;
    if (i >= Gg * 128) return;
    int g = i >> 7, c = i & 127;
    float cn  = cnt[g];
    float m   = sumx[i] / cn;
    float msq = sumxx[i] / cn;
    float sc  = s[c];
    // E[(x - sc*m)^2] = E[x^2] - (2*sc - sc^2) * m^2  (exact rewrite of reference)
    float varo = msq - (2.f * sc - sc * sc) * m * m;
    float inv  = rsqrtf(varo + EPS_GN);
    float Ai   = inv * w[c];
    Ab[i] = Ai;
    Bb[i] = b[c] - sc * m * Ai;
    __syncthreads();          // all reads of cnt[g] in this block done
    sumx[i] = 0.f;
    sumxx[i] = 0.f;
    if (c == 0) cnt[g] = 0.f; // g's 128 threads live in this block
}

__global__ __launch_bounds__(256) void gn_apply(const unsigned int* __restrict__ xb,
                                                const int* __restrict__ batch,
                                                const float* __restrict__ Ab,
                                                const float* __restrict__ Bb,
                                                float* __restrict__ out) {
    int idx = blockIdx.x * 256 + threadIdx.x;
    int n = idx >> 5;
    if (n >= Nn) return;
    int c4 = (idx & 31) << 2;
    int g = batch[n];
    uint2 xv = *(const uint2*)(xb + (size_t)n * 64 + (c4 >> 1));
    float4 Av = *(const float4*)(Ab + g * 128 + c4);
    float4 Bv = *(const float4*)(Bb + g * 128 + c4);
    float4 o;
    o.x = bf_lo(xv.x) * Av.x + Bv.x;
    o.y = bf_hi(xv.x) * Av.y + Bv.y;
    o.z = bf_lo(xv.y) * Av.z + Bv.z;
    o.w = bf_hi(xv.y) * Av.w + Bv.w;
    *(float4*)(out + (size_t)n * 128 + c4) = o;
}

// ---------------------------------------------------------------------------
// Launch
// ---------------------------------------------------------------------------
extern "C" void kernel_launch(void* const* d_in, const int* in_sizes, int n_in,
                              void* d_out, int out_size, void* d_ws, size_t ws_size,
                              hipStream_t stream) {
    const float* x      = (const float*)d_in[0];
    const int*   eidx   = (const int*)d_in[1];
    const int*   batch  = (const int*)d_in[2];
    const float* in_W   = (const float*)d_in[3];
    const float* in_b   = (const float*)d_in[4];
    const float* Wg     = (const float*)d_in[5];
    const float* attS   = (const float*)d_in[6];
    const float* attD   = (const float*)d_in[7];
    const float* gat_b  = (const float*)d_in[8];
    const float* gn_w   = (const float*)d_in[9];
    const float* gn_b   = (const float*)d_in[10];
    const float* gn_s   = (const float*)d_in[11];

    const int* esrc = eidx;
    const int* edst = eidx + Ee;

    char* p = (char*)d_ws;
    auto carve = [&](size_t bytes) {
        void* r = (void*)p;
        p += (bytes + 255) & ~(size_t)255;
        return r;
    };
    unsigned int* h0b = (unsigned int*)carve((size_t)Nn * 64 * 4);  // bf16x2 hidden
    unsigned int* hp  = (unsigned int*)carve((size_t)Nn * 64 * 4);  // bf16x2 h' (GEMM out)
    unsigned int* h2b = (unsigned int*)carve((size_t)Nn * 64 * 4);  // bf16x2 layer state
    float* es   = (float*)carve((size_t)Nn * 8 * 4);
    float* ed   = (float*)carve((size_t)Nn * 8 * 4);
    // cnt (adjacency degrees) + GraphNorm stats: one contiguous zeroed region
    int*   cnt  = (int*)carve((size_t)(Nn + Gg * 128 * 2 + 16) * 4);
    float* sumx  = (float*)(cnt + Nn);
    float* sumxx = sumx + Gg * 128;
    float* cntf  = sumx + Gg * 128 * 2;
    float* Abuf = (float*)carve((size_t)Gg * 128 * 4);
    float* Bbuf = (float*)carve((size_t)Gg * 128 * 4);
    int* colPad = (int*)carve((size_t)Nn * DMAX * 4);
    short* Wt0  = (short*)carve((size_t)128 * 64 * 2);
    short* Wtl  = (short*)carve((size_t)4 * 128 * 128 * 2);

    // ---- weight prep + adjacency build ----
    prep_w<<<288, 256, 0, stream>>>(in_W, Wg, Wt0, Wtl);
    hipMemsetAsync(cnt, 0, (size_t)(Nn + Gg * 128 * 2 + 16) * 4, stream);
    scatter_pad<<<8192, 256, 0, stream>>>(esrc, edst, cnt, colPad);

    const int gemm_grid = (Nn + 127) / 128;  // 391
    const int gat_grid  = 2048;              // persistent grid-stride

    // ---- input projection: x fp32 -> h0b bf16 (+bias) ----
    gemm_mfma<64, false, false, true, false><<<gemm_grid, 256, 0, stream>>>(
        x, nullptr, nullptr, nullptr, nullptr, Wt0, in_b,
        nullptr, nullptr, nullptr, nullptr, h0b, Nn);

    // ---- layers ----
    for (int l = 0; l < 4; l++) {
        const short* Wl = Wtl + (size_t)l * 128 * 128;
        if (l == 0) {
            gemm_mfma<128, true, false, false, true><<<gemm_grid, 256, 0, stream>>>(
                nullptr, h0b, nullptr, nullptr, nullptr, Wl, nullptr,
                attS + l * 128, attD + l * 128, es, ed, hp, Nn);
            gat_attn<false><<<gat_grid, 256, 0, stream>>>(hp, h0b, nullptr, nullptr, nullptr,
                                                          es, ed, cnt, colPad,
                                                          gat_b + l * 128, h2b);
        } else {
            gemm_mfma<128, true, true, false, true><<<gemm_grid, 256, 0, stream>>>(
                nullptr, h2b, batch, Abuf, Bbuf, Wl, nullptr,
                attS + l * 128, attD + l * 128, es, ed, hp, Nn);
            gat_attn<true><<<gat_grid, 256, 0, stream>>>(hp, h2b, batch, Abuf, Bbuf,
                                                         es, ed, cnt, colPad,
                                                         gat_b + l * 128, h2b);
        }
        gn_stats<<<(Nn + SCHUNK - 1) / SCHUNK, 128, 0, stream>>>(h2b, batch, sumx, sumxx, cntf);
        gn_final<<<8, 256, 0, stream>>>(sumx, sumxx, cntf, gn_w + l * 128,
                                        gn_b + l * 128, gn_s + l * 128, Abuf, Bbuf);
    }
    gn_apply<<<(Nn * 32 + 255) / 256, 256, 0, stream>>>(h2b, batch, Abuf, Bbuf,
                                                        (float*)d_out);
    (void)in_sizes; (void)n_in; (void)out_size; (void)ws_size;
}

// Round 6
// 512.011 us; speedup vs baseline: 1.2264x; 1.2264x over previous
//
#include <hip/hip_runtime.h>
#include <cstdint>
#include <cstddef>

#define Nn   50000
#define Ee   800000
#define ETOT 850000   // edges + self loops
#define HID  128
#define Gg   16
#define RSZ  6250     // Nn/8 : dst-range size per XCD team
#define DMAX 64       // padded adjacency slots per node (max degree ~45 for this graph)
#define NEG_SLOPE 0.2f
#define EPS_GN 1e-5f

typedef __attribute__((ext_vector_type(8))) short short8;
typedef __attribute__((ext_vector_type(4))) float f32x4;

static __device__ __forceinline__ float lrelu(float v) { return v > 0.f ? v : NEG_SLOPE * v; }

// round-to-nearest-even fp32 -> bf16 (low 16 bits of uint)
static __device__ __forceinline__ unsigned int f2bf(float x) {
    unsigned int u = __float_as_uint(x);
    return (u + 0x7fffu + ((u >> 16) & 1u)) >> 16;
}
static __device__ __forceinline__ float bf_lo(unsigned int u) { return __uint_as_float(u << 16); }
static __device__ __forceinline__ float bf_hi(unsigned int u) { return __uint_as_float(u & 0xffff0000u); }

// ---------------------------------------------------------------------------
// Weight prep: bf16 transpose of in_W [64][128]->Wt0[128][64] and
// Wg[4][128][128]->Wtl[4][128][128] ([n][k] layout)
// ---------------------------------------------------------------------------
__global__ void prep_w(const float* __restrict__ in_W, const float* __restrict__ Wg,
                       short* __restrict__ Wt0, short* __restrict__ Wtl) {
    int i = blockIdx.x * 256 + threadIdx.x;
    if (i < 8192) {                       // in-proj: n = i>>6, k = i&63
        int n = i >> 6, k = i & 63;
        Wt0[i] = (short)f2bf(in_W[k * 128 + n]);
    } else if (i < 73728) {
        int j = i - 8192;                 // j = l*16384 + n*128 + k
        int l = j >> 14;
        int rkn = j & 16383;
        int n = rkn >> 7, k = rkn & 127;
        Wtl[j] = (short)f2bf(Wg[l * 16384 + k * 128 + n]);
    }
}

// ---------------------------------------------------------------------------
// Padded adjacency build, single pass, XCD-partitioned (block b&7 = dst range,
// so cnt/colPad cache lines have a single-XCD writer).
// R0: 8192 blocks (team traffic is grid-invariant), int4 scan, self-loops as a
// separate team-local loop. Verified: dropped out of top-5.
// ---------------------------------------------------------------------------
__global__ __launch_bounds__(256) void scatter_pad(const int* __restrict__ esrc,
                                                   const int* __restrict__ edst,
                                                   int* __restrict__ cnt,
                                                   int* __restrict__ colPad) {
    int r  = blockIdx.x & 7;
    int cb = blockIdx.x >> 3;
    int nb = gridDim.x >> 3;
    int lo = r * RSZ, hi = lo + RSZ;
    int stride = nb * 256 * 4;
    for (int i = (cb * 256 + threadIdx.x) * 4; i < Ee; i += stride) {
        int4 d4 = *(const int4*)(edst + i);
        bool m0 = (d4.x >= lo) & (d4.x < hi);
        bool m1 = (d4.y >= lo) & (d4.y < hi);
        bool m2 = (d4.z >= lo) & (d4.z < hi);
        bool m3 = (d4.w >= lo) & (d4.w < hi);
        if (m0 | m1 | m2 | m3) {
            int4 s4 = *(const int4*)(esrc + i);
            if (m0) { int pos = atomicAdd(&cnt[d4.x], 1); if (pos < DMAX) colPad[d4.x * DMAX + pos] = s4.x; }
            if (m1) { int pos = atomicAdd(&cnt[d4.y], 1); if (pos < DMAX) colPad[d4.y * DMAX + pos] = s4.y; }
            if (m2) { int pos = atomicAdd(&cnt[d4.z], 1); if (pos < DMAX) colPad[d4.z * DMAX + pos] = s4.z; }
            if (m3) { int pos = atomicAdd(&cnt[d4.w], 1); if (pos < DMAX) colPad[d4.w * DMAX + pos] = s4.w; }
        }
    }
    // self-loops: each team owns its dst range; dst == src == n, no edge loads
    for (int n = lo + cb * 256 + threadIdx.x; n < hi; n += nb * 256) {
        int pos = atomicAdd(&cnt[n], 1);
        if (pos < DMAX) colPad[n * DMAX + pos] = n;
    }
}

// ---------------------------------------------------------------------------
// MFMA bf16 GEMM: C[M,128] = affine?(A)[M,K] @ W[K,128] (+bias), bf16x2 out.
// Block 128x128, 4 waves (2x2 of 64x64), 16x16x32 bf16 MFMA.
// ABF16: A is packed bf16x2 [M, K/2 uints]; else fp32 [M,K].
// SCORES: fused es/ed (attention logits) computed during the repack read-out.
// ---------------------------------------------------------------------------
template <int K, bool ABF16, bool AFFINE, bool BIAS, bool SCORES>
__global__ __launch_bounds__(256) void gemm_mfma(const float* __restrict__ Agf,
                                                 const unsigned int* __restrict__ Agb,
                                                 const int* __restrict__ batch,
                                                 const float* __restrict__ Ab,
                                                 const float* __restrict__ Bb,
                                                 const short* __restrict__ Wt,
                                                 const float* __restrict__ bias,
                                                 const float* __restrict__ asrc,
                                                 const float* __restrict__ adst,
                                                 float* __restrict__ es,
                                                 float* __restrict__ ed,
                                                 unsigned int* __restrict__ Cb,
                                                 int M) {
    constexpr int KP = K + 8;                    // padded shorts per A row
    constexpr int ABYTES = 128 * KP * 2;
    constexpr int CBYTES = 64 * 130 * 4;
    constexpr int SBYTES = ABYTES > CBYTES ? ABYTES : CBYTES;
    __shared__ __align__(16) char smem[SBYTES];
    short* As = (short*)smem;
    float* Cs = (float*)smem;   // overlays As (used only after all MFMA reads)

    int t    = threadIdx.x;
    int lane = t & 63;
    int w    = t >> 6;
    int wm   = (w & 1) * 64;
    int wn   = (w >> 1) * 64;
    int row0 = blockIdx.x * 128;

    // ---- stage A -> bf16 LDS ----
    if (!ABF16) {
        constexpr int F4R = K / 4;               // float4 per row
        constexpr int ITERS = 128 * F4R / 256;
#pragma unroll
        for (int i = 0; i < ITERS; i++) {
            int f4 = t + 256 * i;
            int r  = f4 / F4R;
            int c4 = f4 % F4R;
            float4 v = make_float4(0.f, 0.f, 0.f, 0.f);
            int gr = row0 + r;
            if (gr < M) v = *(const float4*)(Agf + (size_t)gr * K + c4 * 4);
            uint2 pk;
            pk.x = f2bf(v.x) | (f2bf(v.y) << 16);
            pk.y = f2bf(v.z) | (f2bf(v.w) << 16);
            *(uint2*)(As + r * KP + c4 * 4) = pk;
        }
    } else {
        constexpr int U2R = K / 4;               // uint2 per row
        constexpr int ITERS = 128 * U2R / 256;
#pragma unroll
        for (int i = 0; i < ITERS; i++) {
            int u2 = t + 256 * i;
            int r  = u2 / U2R;
            int c2 = u2 % U2R;                   // uint2 index: channels c2*4..+3
            uint2 v = make_uint2(0u, 0u);
            int gr = row0 + r;
            if (gr < M) {
                v = *(const uint2*)(Agb + (size_t)gr * (K / 2) + c2 * 2);
                if (AFFINE) {
                    int g = batch[gr];
                    float4 Av = *(const float4*)(Ab + g * 128 + c2 * 4);
                    float4 Bv = *(const float4*)(Bb + g * 128 + c2 * 4);
                    float x0 = bf_lo(v.x) * Av.x + Bv.x;
                    float x1 = bf_hi(v.x) * Av.y + Bv.y;
                    float x2 = bf_lo(v.y) * Av.z + Bv.z;
                    float x3 = bf_hi(v.y) * Av.w + Bv.w;
                    v.x = f2bf(x0) | (f2bf(x1) << 16);
                    v.y = f2bf(x2) | (f2bf(x3) << 16);
                }
            }
            *(uint2*)(As + r * KP + c2 * 4) = v;
        }
    }
    __syncthreads();

    // ---- MFMA main loop ----
    f32x4 acc[4][4] = {};
    int am = wm + (lane & 15);
    int aq = (lane >> 4) * 8;
    const short* wb = Wt + (size_t)(wn + (lane & 15)) * K + aq;
#pragma unroll
    for (int kk = 0; kk < K / 32; kk++) {
        short8 a[4], b[4];
#pragma unroll
        for (int nt = 0; nt < 4; nt++)
            b[nt] = *(const short8*)(wb + nt * 16 * K + kk * 32);
#pragma unroll
        for (int mt = 0; mt < 4; mt++)
            a[mt] = *(const short8*)(As + (am + mt * 16) * KP + kk * 32 + aq);
#pragma unroll
        for (int mt = 0; mt < 4; mt++)
#pragma unroll
            for (int nt = 0; nt < 4; nt++)
                acc[mt][nt] = __builtin_amdgcn_mfma_f32_16x16x32_bf16(
                    a[mt], b[nt], acc[mt][nt], 0, 0, 0);
    }

    // ---- epilogue: LDS repack -> packed bf16x2 (+bias, + fused scores) ----
    // C/D layout: col = lane&15 (within 16-tile), row = (lane>>4)*4 + reg
    float bv[4] = {0.f, 0.f, 0.f, 0.f};
    if (BIAS) {
#pragma unroll
        for (int nt = 0; nt < 4; nt++) bv[nt] = bias[wn + nt * 16 + (lane & 15)];
    }
    float avv[8], dvv[8];
    if (SCORES) {
        int q = t & 15;
#pragma unroll
        for (int k = 0; k < 8; k++) {
            avv[k] = asrc[q * 8 + k];
            dvv[k] = adst[q * 8 + k];
        }
    }
#pragma unroll
    for (int half = 0; half < 2; half++) {
        __syncthreads();   // As reads done / previous pack done
        if ((w & 1) == half) {
#pragma unroll
            for (int mt = 0; mt < 4; mt++)
#pragma unroll
                for (int reg = 0; reg < 4; reg++) {
                    int lr = mt * 16 + (lane >> 4) * 4 + reg;   // 0..63
#pragma unroll
                    for (int nt = 0; nt < 4; nt++)
                        Cs[lr * 130 + wn + nt * 16 + (lane & 15)] =
                            acc[mt][nt][reg] + bv[nt];
                }
        }
        __syncthreads();
#pragma unroll
        for (int i = 0; i < 4; i++) {
            int u4 = t + 256 * i;       // 0..1023
            int r  = u4 >> 4;           // 0..63
            int cu = (u4 & 15) * 4;     // uint col
            int grow = row0 + half * 64 + r;
            if (grow < M) {
                const float* cp = Cs + r * 130 + cu * 2;
                float2 p0 = *(const float2*)(cp + 0);
                float2 p1 = *(const float2*)(cp + 2);
                float2 p2 = *(const float2*)(cp + 4);
                float2 p3 = *(const float2*)(cp + 6);
                uint4 o;
                o.x = f2bf(p0.x) | (f2bf(p0.y) << 16);
                o.y = f2bf(p1.x) | (f2bf(p1.y) << 16);
                o.z = f2bf(p2.x) | (f2bf(p2.y) << 16);
                o.w = f2bf(p3.x) | (f2bf(p3.y) << 16);
                *(uint4*)(Cb + (size_t)grow * 64 + cu) = o;
                if (SCORES) {
                    float s1 = p0.x * avv[0] + p0.y * avv[1] + p1.x * avv[2] +
                               p1.y * avv[3] + p2.x * avv[4] + p2.y * avv[5] +
                               p3.x * avv[6] + p3.y * avv[7];
                    float s2 = p0.x * dvv[0] + p0.y * dvv[1] + p1.x * dvv[2] +
                               p1.y * dvv[3] + p2.x * dvv[4] + p2.y * dvv[5] +
                               p3.x * dvv[6] + p3.y * dvv[7];
                    s1 += __shfl_xor(s1, 1);
                    s2 += __shfl_xor(s2, 1);
                    if ((t & 1) == 0) {
                        int hh = (t & 15) >> 1;
                        es[(size_t)grow * 8 + hh] = s1;
                        ed[(size_t)grow * 8 + hh] = s2;
                    }
                }
            }
        }
    }
}

// ---------------------------------------------------------------------------
// GAT aggregation. One wave per destination node. R5: REVERT to the R1 kernel
// (best measured: 44.3 us). History: R1 uint4/4-edge = 44.3; R2 full-unroll
// intent = compiler re-fused (VGPR 28), 50.9; R3 phase-split via pre-normalize
// = reached codegen (VGPR 44) but serial-persistent structure collapsed
// occupancy (38%) -> 74 us. Conclusion: the interleaved per-group schedule +
// 50k one-node waves is the best structure; ~44 us / ~3 TB/s beyond-L2 is the
// pattern's throughput equilibrium (3 structurally different impls pin here).
// Lane roles: weight (slot=lane>>3, head=lane&7); accumulate (q=lane>>4,
// s=lane&15 holds channels 8s..8s+7, uint4 gather); head hd = s>>1.
// ---------------------------------------------------------------------------
template <bool AFF>
__global__ __launch_bounds__(256) void gat_attn(const unsigned int* __restrict__ hp,
                                                const unsigned int* hinb,
                                                const int* __restrict__ batch,
                                                const float* __restrict__ Ab,
                                                const float* __restrict__ Bb,
                                                const float* __restrict__ es,
                                                const float* __restrict__ ed,
                                                const int* __restrict__ cnt,
                                                const int* __restrict__ colPad,
                                                const float* __restrict__ gbias,
                                                unsigned int* outb) {
    int w    = threadIdx.x >> 6;
    int lane = threadIdx.x & 63;
    int n    = blockIdx.x * 4 + w;
    int deg  = cnt[n];
    deg = deg < DMAX ? deg : DMAX;
    const int* cb = colPad + n * DMAX;

    int slot = lane >> 3;   // edge slot (weight phase)
    int ah   = lane & 7;    // head (weight phase)
    int q    = lane >> 4;   // edge parity mod 4 (accumulate phase)
    int s    = lane & 15;   // channel group: channels 8s .. 8s+7 (uint4 index s)
    int hd   = s >> 1;      // head of this lane's channels

    float edh = ed[(size_t)n * 8 + ah];
    const uint4* hp4 = (const uint4*)hp + s;    // + sj*16 per row

    float a0 = 0.f, a1 = 0.f, a2 = 0.f, a3 = 0.f;
    float a4 = 0.f, a5 = 0.f, a6 = 0.f, a7 = 0.f;
    float dacc = 0.f;

    int e0 = 0;
    for (; e0 + 8 <= deg; e0 += 8) {
        int src_l = cb[e0 + slot];
        float wgt = __expf(lrelu(es[(size_t)src_l * 8 + ah] + edh));
        dacc += wgt;
#pragma unroll
        for (int jj = 0; jj < 2; jj++) {
            int e = jj * 4 + q;
            int   sj = __shfl(src_l, e * 8);
            float wj = __shfl(wgt,   e * 8 + hd);
            uint4 hv = hp4[(size_t)sj * 16];
            a0 += wj * bf_lo(hv.x);
            a1 += wj * bf_hi(hv.x);
            a2 += wj * bf_lo(hv.y);
            a3 += wj * bf_hi(hv.y);
            a4 += wj * bf_lo(hv.z);
            a5 += wj * bf_hi(hv.z);
            a6 += wj * bf_lo(hv.w);
            a7 += wj * bf_hi(hv.w);
        }
    }
    if (e0 < deg) {
        int rem = deg - e0;                       // 1..7, wave-uniform
        int ee  = e0 + slot;
        int ec  = (slot < rem) ? ee : (deg - 1);  // rows non-empty (self-loop)
        int src_l = cb[ec];
        float wgt = (slot < rem) ? __expf(lrelu(es[(size_t)src_l * 8 + ah] + edh)) : 0.f;
        dacc += wgt;
        int steps = (rem + 3) >> 2;
        for (int jj = 0; jj < steps; jj++) {      // uniform trip count
            int e = jj * 4 + q;                   // weights beyond rem are 0
            int   sj = __shfl(src_l, e * 8);
            float wj = __shfl(wgt,   e * 8 + hd);
            uint4 hv = hp4[(size_t)sj * 16];
            a0 += wj * bf_lo(hv.x);
            a1 += wj * bf_hi(hv.x);
            a2 += wj * bf_lo(hv.y);
            a3 += wj * bf_hi(hv.y);
            a4 += wj * bf_lo(hv.z);
            a5 += wj * bf_hi(hv.z);
            a6 += wj * bf_lo(hv.w);
            a7 += wj * bf_hi(hv.w);
        }
    }

    // combine the four quarters (each saw edges of one parity mod 4)
    a0 += __shfl_xor(a0, 16); a0 += __shfl_xor(a0, 32);
    a1 += __shfl_xor(a1, 16); a1 += __shfl_xor(a1, 32);
    a2 += __shfl_xor(a2, 16); a2 += __shfl_xor(a2, 32);
    a3 += __shfl_xor(a3, 16); a3 += __shfl_xor(a3, 32);
    a4 += __shfl_xor(a4, 16); a4 += __shfl_xor(a4, 32);
    a5 += __shfl_xor(a5, 16); a5 += __shfl_xor(a5, 32);
    a6 += __shfl_xor(a6, 16); a6 += __shfl_xor(a6, 32);
    a7 += __shfl_xor(a7, 16); a7 += __shfl_xor(a7, 32);

    // denominator: sum over the 8 slots sharing head `ah`
    dacc += __shfl_xor(dacc, 8);
    dacc += __shfl_xor(dacc, 16);
    dacc += __shfl_xor(dacc, 32);
    float inv  = 1.0f / (dacc + 1e-16f);
    float winv = __shfl(inv, hd);       // lane hd has ah == hd

    if (q == 0) {
        size_t uo = (size_t)n * 64 + s * 4;
        uint4 xv = *(const uint4*)(hinb + uo);
        float r0 = bf_lo(xv.x), r1 = bf_hi(xv.x), r2 = bf_lo(xv.y), r3 = bf_hi(xv.y);
        float r4 = bf_lo(xv.z), r5 = bf_hi(xv.z), r6 = bf_lo(xv.w), r7 = bf_hi(xv.w);
        float4 bv0 = *(const float4*)(gbias + s * 8);
        float4 bv1 = *(const float4*)(gbias + s * 8 + 4);
        if (AFF) {
            int g = batch[n];
            float4 Av0 = *(const float4*)(Ab + g * 128 + s * 8);
            float4 Bv0 = *(const float4*)(Bb + g * 128 + s * 8);
            float4 Av1 = *(const float4*)(Ab + g * 128 + s * 8 + 4);
            float4 Bv1 = *(const float4*)(Bb + g * 128 + s * 8 + 4);
            r0 = r0 * Av0.x + Bv0.x;
            r1 = r1 * Av0.y + Bv0.y;
            r2 = r2 * Av0.z + Bv0.z;
            r3 = r3 * Av0.w + Bv0.w;
            r4 = r4 * Av1.x + Bv1.x;
            r5 = r5 * Av1.y + Bv1.y;
            r6 = r6 * Av1.z + Bv1.z;
            r7 = r7 * Av1.w + Bv1.w;
        }
        float o0 = a0 * winv + bv0.x + r0;
        float o1 = a1 * winv + bv0.y + r1;
        float o2 = a2 * winv + bv0.z + r2;
        float o3 = a3 * winv + bv0.w + r3;
        float o4 = a4 * winv + bv1.x + r4;
        float o5 = a5 * winv + bv1.y + r5;
        float o6 = a6 * winv + bv1.z + r6;
        float o7 = a7 * winv + bv1.w + r7;
        uint4 o;
        o.x = f2bf(o0) | (f2bf(o1) << 16);
        o.y = f2bf(o2) | (f2bf(o3) << 16);
        o.z = f2bf(o4) | (f2bf(o5) << 16);
        o.w = f2bf(o6) | (f2bf(o7) << 16);
        *(uint4*)(outb + uo) = o;
    }
}

// ---------------------------------------------------------------------------
// GraphNorm stats (bf16 input): per (g,c) sum/sumsq; batch sorted -> run flush.
// ---------------------------------------------------------------------------
#define SCHUNK 32
__global__ __launch_bounds__(128) void gn_stats(const unsigned int* __restrict__ xb,
                                                const int* __restrict__ batch,
                                                float* __restrict__ sumx,
                                                float* __restrict__ sumxx,
                                                float* __restrict__ cnt) {
    int c  = threadIdx.x;
    int cu = c >> 1;
    int hi = c & 1;
    int n0 = blockIdx.x * SCHUNK;
    int n1 = n0 + SCHUNK;
    if (n1 > Nn) n1 = Nn;
    if (n0 >= Nn) return;
    int curG = batch[n0];
    float sx = 0.f, sxx = 0.f;
    int run = 0;
    for (int n = n0; n < n1; n++) {
        int g = batch[n];
        if (g != curG) {
            atomicAdd(&sumx[curG * 128 + c], sx);
            atomicAdd(&sumxx[curG * 128 + c], sxx);
            if (c == 0) atomicAdd(&cnt[curG], (float)run);
            sx = 0.f; sxx = 0.f; run = 0; curG = g;
        }
        unsigned int u = xb[(size_t)n * 64 + cu];
        float v = hi ? bf_hi(u) : bf_lo(u);
        sx += v; sxx += v * v; run++;
    }
    atomicAdd(&sumx[curG * 128 + c], sx);
    atomicAdd(&sumxx[curG * 128 + c], sxx);
    if (c == 0) atomicAdd(&cnt[curG], (float)run);
}

// computes Ab/Bb then zeroes sumx/sumxx/cnt for the next layer's gn_stats
__global__ void gn_final(float* __restrict__ sumx, float* __restrict__ sumxx,
                         float* __restrict__ cnt, const float* __restrict__ w,
                         const float* __restrict__ b, const float* __restrict__ s,
                         float* __restrict__ Ab, float* __restrict__ Bb) {
    int i = blockIdx.x * blockDim.x + threadIdx.x;
    if (i >= Gg * 128) return;
    int g = i >> 7, c = i & 127;
    float cn  = cnt[g];
    float m   = sumx[i] / cn;
    float msq = sumxx[i] / cn;
    float sc  = s[c];
    // E[(x - sc*m)^2] = E[x^2] - (2*sc - sc^2) * m^2  (exact rewrite of reference)
    float varo = msq - (2.f * sc - sc * sc) * m * m;
    float inv  = rsqrtf(varo + EPS_GN);
    float Ai   = inv * w[c];
    Ab[i] = Ai;
    Bb[i] = b[c] - sc * m * Ai;
    __syncthreads();          // all reads of cnt[g] in this block done
    sumx[i] = 0.f;
    sumxx[i] = 0.f;
    if (c == 0) cnt[g] = 0.f; // g's 128 threads live in this block
}

__global__ __launch_bounds__(256) void gn_apply(const unsigned int* __restrict__ xb,
                                                const int* __restrict__ batch,
                                                const float* __restrict__ Ab,
                                                const float* __restrict__ Bb,
                                                float* __restrict__ out) {
    int idx = blockIdx.x * 256 + threadIdx.x;
    int n = idx >> 5;
    if (n >= Nn) return;
    int c4 = (idx & 31) << 2;
    int g = batch[n];
    uint2 xv = *(const uint2*)(xb + (size_t)n * 64 + (c4 >> 1));
    float4 Av = *(const float4*)(Ab + g * 128 + c4);
    float4 Bv = *(const float4*)(Bb + g * 128 + c4);
    float4 o;
    o.x = bf_lo(xv.x) * Av.x + Bv.x;
    o.y = bf_hi(xv.x) * Av.y + Bv.y;
    o.z = bf_lo(xv.y) * Av.z + Bv.z;
    o.w = bf_hi(xv.y) * Av.w + Bv.w;
    *(float4*)(out + (size_t)n * 128 + c4) = o;
}

// ---------------------------------------------------------------------------
// Launch
// ---------------------------------------------------------------------------
extern "C" void kernel_launch(void* const* d_in, const int* in_sizes, int n_in,
                              void* d_out, int out_size, void* d_ws, size_t ws_size,
                              hipStream_t stream) {
    const float* x      = (const float*)d_in[0];
    const int*   eidx   = (const int*)d_in[1];
    const int*   batch  = (const int*)d_in[2];
    const float* in_W   = (const float*)d_in[3];
    const float* in_b   = (const float*)d_in[4];
    const float* Wg     = (const float*)d_in[5];
    const float* attS   = (const float*)d_in[6];
    const float* attD   = (const float*)d_in[7];
    const float* gat_b  = (const float*)d_in[8];
    const float* gn_w   = (const float*)d_in[9];
    const float* gn_b   = (const float*)d_in[10];
    const float* gn_s   = (const float*)d_in[11];

    const int* esrc = eidx;
    const int* edst = eidx + Ee;

    char* p = (char*)d_ws;
    auto carve = [&](size_t bytes) {
        void* r = (void*)p;
        p += (bytes + 255) & ~(size_t)255;
        return r;
    };
    unsigned int* h0b = (unsigned int*)carve((size_t)Nn * 64 * 4);  // bf16x2 hidden
    unsigned int* hp  = (unsigned int*)carve((size_t)Nn * 64 * 4);  // bf16x2 h' (GEMM out)
    unsigned int* h2b = (unsigned int*)carve((size_t)Nn * 64 * 4);  // bf16x2 layer state
    float* es   = (float*)carve((size_t)Nn * 8 * 4);
    float* ed   = (float*)carve((size_t)Nn * 8 * 4);
    // cnt (adjacency degrees) + GraphNorm stats: one contiguous zeroed region
    int*   cnt  = (int*)carve((size_t)(Nn + Gg * 128 * 2 + 16) * 4);
    float* sumx  = (float*)(cnt + Nn);
    float* sumxx = sumx + Gg * 128;
    float* cntf  = sumx + Gg * 128 * 2;
    float* Abuf = (float*)carve((size_t)Gg * 128 * 4);
    float* Bbuf = (float*)carve((size_t)Gg * 128 * 4);
    int* colPad = (int*)carve((size_t)Nn * DMAX * 4);
    short* Wt0  = (short*)carve((size_t)128 * 64 * 2);
    short* Wtl  = (short*)carve((size_t)4 * 128 * 128 * 2);

    // ---- weight prep + adjacency build ----
    prep_w<<<288, 256, 0, stream>>>(in_W, Wg, Wt0, Wtl);
    hipMemsetAsync(cnt, 0, (size_t)(Nn + Gg * 128 * 2 + 16) * 4, stream);
    scatter_pad<<<8192, 256, 0, stream>>>(esrc, edst, cnt, colPad);

    const int gemm_grid = (Nn + 127) / 128;  // 391

    // ---- input projection: x fp32 -> h0b bf16 (+bias) ----
    gemm_mfma<64, false, false, true, false><<<gemm_grid, 256, 0, stream>>>(
        x, nullptr, nullptr, nullptr, nullptr, Wt0, in_b,
        nullptr, nullptr, nullptr, nullptr, h0b, Nn);

    // ---- layers ----
    for (int l = 0; l < 4; l++) {
        const short* Wl = Wtl + (size_t)l * 128 * 128;
        if (l == 0) {
            gemm_mfma<128, true, false, false, true><<<gemm_grid, 256, 0, stream>>>(
                nullptr, h0b, nullptr, nullptr, nullptr, Wl, nullptr,
                attS + l * 128, attD + l * 128, es, ed, hp, Nn);
            gat_attn<false><<<Nn / 4, 256, 0, stream>>>(hp, h0b, nullptr, nullptr, nullptr,
                                                        es, ed, cnt, colPad,
                                                        gat_b + l * 128, h2b);
        } else {
            gemm_mfma<128, true, true, false, true><<<gemm_grid, 256, 0, stream>>>(
                nullptr, h2b, batch, Abuf, Bbuf, Wl, nullptr,
                attS + l * 128, attD + l * 128, es, ed, hp, Nn);
            gat_attn<true><<<Nn / 4, 256, 0, stream>>>(hp, h2b, batch, Abuf, Bbuf,
                                                       es, ed, cnt, colPad,
                                                       gat_b + l * 128, h2b);
        }
        gn_stats<<<(Nn + SCHUNK - 1) / SCHUNK, 128, 0, stream>>>(h2b, batch, sumx, sumxx, cntf);
        gn_final<<<8, 256, 0, stream>>>(sumx, sumxx, cntf, gn_w + l * 128,
                                        gn_b + l * 128, gn_s + l * 128, Abuf, Bbuf);
    }
    gn_apply<<<(Nn * 32 + 255) / 256, 256, 0, stream>>>(h2b, batch, Abuf, Bbuf,
                                                        (float*)d_out);
    (void)in_sizes; (void)n_in; (void)out_size; (void)ws_size;
}